// Round 1
// baseline (418.379 us; speedup 1.0000x reference)
//
#include <hip/hip_runtime.h>
#include <math.h>

#define D 128
#define MAXNORM 0.996f            // (1 - 4e-3)/sqrt(c), c = 1
#define MINNORM 1e-15f
#define ATCLAMP (1.0f - 1e-7f)

typedef unsigned int   u32;
typedef unsigned short u16;

typedef __attribute__((ext_vector_type(8))) short bf16x8;
typedef __attribute__((ext_vector_type(4))) float f32x4;

__device__ __forceinline__ float wsum(float v) {
#pragma unroll
  for (int m = 32; m; m >>= 1) v += __shfl_xor(v, m);
  return v;
}
// 16-lane reduction (stays within a lane&48 group) — matches MFMA C-layout rows
__device__ __forceinline__ float rsum16(float v) {
#pragma unroll
  for (int m = 1; m <= 8; m <<= 1) v += __shfl_xor(v, m);
  return v;
}

__device__ __forceinline__ float frcp(float x) { return __builtin_amdgcn_rcpf(x); }

// fast artanh for x in [0, 1-1e-7]
__device__ __forceinline__ float fast_artanh(float x) {
  x = fminf(x, ATCLAMP);
  return 0.5f * __logf((1.0f + x) * frcp(1.0f - x));
}
// fast tanh for z >= 0
__device__ __forceinline__ float fast_tanh(float z) {
  float t = __expf(-2.0f * z);
  return (1.0f - t) * frcp(1.0f + t);
}

__device__ __forceinline__ float bflo(u32 u) { return __uint_as_float(u << 16); }
__device__ __forceinline__ float bfhi(u32 u) { return __uint_as_float(u & 0xffff0000u); }
__device__ __forceinline__ u16 f2bf(float f) {            // RNE f32 -> bf16
  u32 u = __float_as_uint(f);
  return (u16)((u + 0x7fffu + ((u >> 16) & 1u)) >> 16);
}
__device__ __forceinline__ float bf2f(u16 h) { return __uint_as_float(((u32)h) << 16); }

union U4B8 { uint4 u; bf16x8 b; };
__device__ __forceinline__ bf16x8 as_b8(uint4 v) { U4B8 c; c.u = v; return c.b; }

// ---- runtime dtype detection (wave-uniform; call before any divergence) ----
__device__ __forceinline__ bool detect_bf16(const u32* p) {
  float lo = fabsf(bflo(p[threadIdx.x & 63]));
  return (bool)__all(lo < 1.0f);
}
__device__ __forceinline__ bool detect_i64(const int* p) {
  return (bool)__all(p[2 * (threadIdx.x & 63) + 1] == 0);
}

// ---------------- K0: zero int buffer ----------------
extern "C" __global__ __launch_bounds__(256) void k0_zeroi(int* p, int n) {
  int i = blockIdx.x * 256 + threadIdx.x;
  if (i < n) p[i] = 0;
}

// ====== K1: MFMA mobius_matvec + proj + mobius_add(bias) + proj + logmap0 ======
// One 16-row x 128-col output tile per wave via mfma_f32_16x16x32_bf16.
// W staged in LDS pre-swizzled into B-fragment order (conflict-free ds_read_b128).
// fp32 inputs use bf16x3 split (xh*wh + xl*wh + xh*wl), rel err ~2^-16 — far
// below the bf16 quantization of xt that downstream already tolerates.
// A/B k-ordering correctness: A and B fragments are loaded with the SAME
// k->slot bijection, so the dot product is invariant to HW internal k order.
// C layout (m89-verified): col = lane&15, row = (lane>>4)*4 + reg.
template<bool BF>
__device__ __forceinline__ void k1_body(const void* xv, const void* Wv,
                                        const void* bv, u16* xt, int N,
                                        uint4* Wh, uint4* Wl) {
  const int tid  = threadIdx.x;
  const int lane = tid & 63;
  const int wid  = tid >> 6;
  const int qg   = lane >> 4;   // k-block group 0..3
  const int lc   = lane & 15;   // col within 16-wide tile

  // ---- stage W in fragment order: slot = (t*4+ks)*64 + l
  //      holds W[(l&15)+16t, 32*ks + 8*(l>>4) .. +8] as 8 bf16 (16B)
  for (int slot = tid; slot < 2048; slot += 256) {
    const int l = slot & 63, frag = slot >> 6;
    const int t = frag >> 2, ks = frag & 3;
    const int j  = (l & 15) + 16 * t;
    const int k0 = 32 * ks + 8 * (l >> 4);
    if (BF) {
      Wh[slot] = ((const uint4*)Wv)[j * 16 + (k0 >> 3)];
    } else {
      const float* Wf = (const float*)Wv;
      float4 f0 = *(const float4*)(Wf + (size_t)j * D + k0);
      float4 f1 = *(const float4*)(Wf + (size_t)j * D + k0 + 4);
      float f[8] = {f0.x, f0.y, f0.z, f0.w, f1.x, f1.y, f1.z, f1.w};
      u32 hw[4], lw[4];
#pragma unroll
      for (int i = 0; i < 4; ++i) {
        u16 h0 = f2bf(f[2*i]),  h1 = f2bf(f[2*i+1]);
        u16 l0 = f2bf(f[2*i]   - bf2f(h0));
        u16 l1 = f2bf(f[2*i+1] - bf2f(h1));
        hw[i] = (u32)h0 | ((u32)h1 << 16);
        lw[i] = (u32)l0 | ((u32)l1 << 16);
      }
      Wh[slot] = make_uint4(hw[0], hw[1], hw[2], hw[3]);
      Wl[slot] = make_uint4(lw[0], lw[1], lw[2], lw[3]);
    }
  }

  // ---- hyp_bias fragment: bfr[t] = proj(expmap0(b))[lc + 16t]
  float bfr[8];
  float nb2 = 0.f;
#pragma unroll
  for (int t = 0; t < 8; ++t) {
    float v = BF ? bf2f(((const u16*)bv)[lc + 16 * t])
                 : ((const float*)bv)[lc + 16 * t];
    bfr[t] = v; nb2 += v * v;
  }
  nb2 = rsum16(nb2);                       // uniform across all lanes (same data)
  float y2;
  {
    float nb = fmaxf(sqrtf(nb2), MINNORM);
    float s  = fast_tanh(nb) * frcp(nb);
    float n1 = s * nb;
    if (n1 > MAXNORM) s *= MAXNORM * frcp(n1);
#pragma unroll
    for (int t = 0; t < 8; ++t) bfr[t] *= s;
    y2 = s * s * nb2;                      // exact 0 when bias is zero
  }
  const bool bias_zero = (y2 == 0.0f);

  __syncthreads();

  const int tile  = blockIdx.x * 4 + wid;
  const int rbase = tile * 16;
  if (rbase >= N) return;

  // ---- A fragments: lane holds row rbase+lc, k = 32*ks + 8*qg .. +8
  int rowA = rbase + lc; if (rowA >= N) rowA = N - 1;
  uint4 Ah[4], Al[4];
  float xn2 = 0.f;
  if (BF) {
    const uint4* xr = (const uint4*)((const u16*)xv + (size_t)rowA * D);
#pragma unroll
    for (int ks = 0; ks < 4; ++ks) {
      uint4 v = xr[4 * ks + qg];
      Ah[ks] = v;
      float a0 = bflo(v.x), a1 = bfhi(v.x), a2 = bflo(v.y), a3 = bfhi(v.y);
      float a4 = bflo(v.z), a5 = bfhi(v.z), a6 = bflo(v.w), a7 = bfhi(v.w);
      xn2 += a0*a0 + a1*a1 + a2*a2 + a3*a3 + a4*a4 + a5*a5 + a6*a6 + a7*a7;
    }
  } else {
    const float4* xr = (const float4*)((const float*)xv + (size_t)rowA * D);
#pragma unroll
    for (int ks = 0; ks < 4; ++ks) {
      float4 f0 = xr[8 * ks + 2 * qg], f1 = xr[8 * ks + 2 * qg + 1];
      float f[8] = {f0.x, f0.y, f0.z, f0.w, f1.x, f1.y, f1.z, f1.w};
      u32 hw[4], lw[4];
#pragma unroll
      for (int i = 0; i < 4; ++i) {
        u16 h0 = f2bf(f[2*i]),  h1 = f2bf(f[2*i+1]);
        u16 l0 = f2bf(f[2*i]   - bf2f(h0));
        u16 l1 = f2bf(f[2*i+1] - bf2f(h1));
        hw[i] = (u32)h0 | ((u32)h1 << 16);
        lw[i] = (u32)l0 | ((u32)l1 << 16);
        xn2 += f[2*i] * f[2*i] + f[2*i+1] * f[2*i+1];
      }
      Ah[ks] = make_uint4(hw[0], hw[1], hw[2], hw[3]);
      Al[ks] = make_uint4(lw[0], lw[1], lw[2], lw[3]);
    }
  }
  // reduce xn2 over the k-groups (lanes lc, lc+16, lc+32, lc+48)
  xn2 += __shfl_xor(xn2, 16);
  xn2 += __shfl_xor(xn2, 32);   // lane r now holds ||x[rbase+r]||^2 (r = lane&15)

  // ---- MFMA: acc[t] is the 16x16 tile at cols 16t..16t+15
  f32x4 acc[8];
  const f32x4 zero = {0.f, 0.f, 0.f, 0.f};
#pragma unroll
  for (int t = 0; t < 8; ++t) acc[t] = zero;
#pragma unroll
  for (int ks = 0; ks < 4; ++ks) {
    bf16x8 a = as_b8(Ah[ks]);
    bf16x8 al;
    if (!BF) al = as_b8(Al[ks]);
#pragma unroll
    for (int t = 0; t < 8; ++t) {
      const int idx = (t * 4 + ks) * 64 + lane;
      bf16x8 bh = as_b8(Wh[idx]);
      acc[t] = __builtin_amdgcn_mfma_f32_16x16x32_bf16(a, bh, acc[t], 0, 0, 0);
      if (!BF) {
        bf16x8 bl = as_b8(Wl[idx]);
        acc[t] = __builtin_amdgcn_mfma_f32_16x16x32_bf16(al, bh, acc[t], 0, 0, 0);
        acc[t] = __builtin_amdgcn_mfma_f32_16x16x32_bf16(a,  bl, acc[t], 0, 0, 0);
      }
    }
  }

  // ---- epilogue in C layout: row = rbase + qg*4 + q, col = lc + 16t
#pragma unroll
  for (int q = 0; q < 4; ++q) {
    const int row_off = qg * 4 + q;
    const int row = rbase + row_off;
    float xnq = fmaxf(sqrtf(__shfl(xn2, row_off)), MINNORM);
    float s2 = 0.f;
#pragma unroll
    for (int t = 0; t < 8; ++t) { float v = acc[t][q]; s2 += v * v; }
    s2 = rsum16(s2);
    float mxn = fmaxf(sqrtf(s2), MINNORM);
    float r = fast_tanh(mxn * frcp(xnq) * fast_artanh(xnq)) * frcp(mxn);
    float pn = r * mxn;
    if (pn > MAXNORM) { r *= MAXNORM * frcp(pn); pn = MAXNORM; }
    float h[8];
    float hn;
    if (bias_zero) {
#pragma unroll
      for (int t = 0; t < 8; ++t) h[t] = r * acc[t][q];
      hn = pn;
    } else {
      float xy = 0.f;
#pragma unroll
      for (int t = 0; t < 8; ++t) { h[t] = r * acc[t][q]; xy += h[t] * bfr[t]; }
      xy = rsum16(xy);
      float x2 = pn * pn;
      float ca = 1.f + 2.f * xy + y2;
      float cb = 1.f - x2;
      float id = frcp(fmaxf(1.f + 2.f * xy + x2 * y2, MINNORM));
      float s3 = 0.f;
#pragma unroll
      for (int t = 0; t < 8; ++t) { h[t] = (ca * h[t] + cb * bfr[t]) * id; s3 += h[t] * h[t]; }
      hn = fmaxf(sqrtf(rsum16(s3)), MINNORM);
    }
    float ps = (hn > MAXNORM) ? (MAXNORM * frcp(hn)) : 1.f;
    float np = fmaxf(hn * ps, MINNORM);
    float tsc = fast_artanh(np) * frcp(np) * ps;
    if (row < N) {
      u16* xo = xt + (size_t)row * D + lc;
#pragma unroll
      for (int t = 0; t < 8; ++t) xo[16 * t] = f2bf(tsc * h[t]);
    }
  }
}

extern "C" __global__ __launch_bounds__(256)
void OriginHyperbolicGraphConvolution_38628935860614_kernel(
    const void* x, const void* W, const void* b, u16* xt, int N) {
  __shared__ uint4 Wh[2048];   // 32 KB: W-hi plane, fragment-ordered
  __shared__ uint4 Wl[2048];   // 32 KB: W-lo plane (fp32 input path only)
  if (detect_bf16((const u32*)x)) k1_body<true >(x, W, b, xt, N, Wh, Wl);
  else                            k1_body<false>(x, W, b, xt, N, Wh, Wl);
}

// ====== K2a: histogram of dst ======
extern "C" __global__ __launch_bounds__(256) void khist(
    const int* ei, int* bins, int E, int N) {
  const bool i64 = detect_i64(ei);
  int e = blockIdx.x * 256 + threadIdx.x;
  if (e >= E) return;
  int dst, src;
  if (i64) { dst = ei[2 * (size_t)e]; src = ei[2 * ((size_t)E + e)]; }
  else     { dst = ei[e];             src = ei[(size_t)E + e]; }
  if ((unsigned)dst < (unsigned)N && (unsigned)src < (unsigned)N)
    atomicAdd(&bins[dst], 1);
}

// ====== K2b/c/d: exclusive scan of bins -> offsets ======
extern "C" __global__ __launch_bounds__(256) void kscan1(
    const int* bins, int* offs, int* part, int N) {
  __shared__ int sc[256];
  const int tid = threadIdx.x;
  const int i = blockIdx.x * 256 + tid;
  int v = (i < N) ? bins[i] : 0;
  sc[tid] = v; __syncthreads();
#pragma unroll
  for (int off = 1; off < 256; off <<= 1) {
    int t = (tid >= off) ? sc[tid - off] : 0;
    __syncthreads();
    sc[tid] += t;
    __syncthreads();
  }
  if (i <= N) offs[i] = sc[tid] - v;
  if (tid == 255) part[blockIdx.x] = sc[255];
}

extern "C" __global__ __launch_bounds__(1024) void kscan2(
    int* part, int* offs, int B, int N) {
  __shared__ int sc[1024];
  const int tid = threadIdx.x;
  int v = (tid < B) ? part[tid] : 0;
  sc[tid] = v; __syncthreads();
#pragma unroll
  for (int off = 1; off < 1024; off <<= 1) {
    int t = (tid >= off) ? sc[tid - off] : 0;
    __syncthreads();
    sc[tid] += t;
    __syncthreads();
  }
  if (tid < B) part[tid] = sc[tid] - v;
  if (tid == 1023) offs[N] = sc[1023];
}

extern "C" __global__ __launch_bounds__(256) void kscan3(
    int* offs, int* cursor, const int* part, int N) {
  const int i = blockIdx.x * 256 + threadIdx.x;
  if (i < N) {
    int o = offs[i] + part[blockIdx.x];
    offs[i] = o;
    cursor[i] = o;
  }
}

// ====== K2e: scatter edges into dst-sorted order, packed (src, w_bits) ======
extern "C" __global__ __launch_bounds__(256) void kscatter(
    const int* ei, const void* ew, int* cursor, uint2* esrt, int E, int N) {
  const bool bf  = detect_bf16((const u32*)ew);
  const bool i64 = detect_i64(ei);
  int e = blockIdx.x * 256 + threadIdx.x;
  if (e >= E) return;
  int dst, src;
  if (i64) { dst = ei[2 * (size_t)e]; src = ei[2 * ((size_t)E + e)]; }
  else     { dst = ei[e];             src = ei[(size_t)E + e]; }
  if ((unsigned)dst >= (unsigned)N || (unsigned)src >= (unsigned)N) return;
  float w;
  if (bf) w = __uint_as_float(((u32)((const u16*)ew)[e]) << 16);
  else    w = ((const float*)ew)[e];
  int pos = atomicAdd(&cursor[dst], 1);
  esrt[pos] = make_uint2((u32)src, __float_as_uint(w));
}

// ====== K3: gather-aggregate per node + fused finalize ======
extern "C" __global__ __launch_bounds__(256) void kagg(
    const int* offs, const uint2* esrt, const u16* xt,
    void* out, const void* xdet, int N) {
  const bool bf = detect_bf16((const u32*)xdet);
  const int lane = threadIdx.x & 63;
  const int node = blockIdx.x * 4 + (threadIdx.x >> 6);
  if (node >= N) return;
  const int s0 = offs[node], s1 = offs[node + 1];
  const u32* xtw = (const u32*)xt;
  float a0 = 0.f, a1 = 0.f;
  for (int base = s0; base < s1; base += 64) {
    const int m = min(64, s1 - base);
    uint2 ed = make_uint2(0u, 0u);
    if (lane < m) ed = esrt[base + lane];    // coalesced 512B edge-chunk load
    int i = 0;
    for (; i + 4 <= m; i += 4) {
      const u32 sA = __shfl(ed.x, i),     sB = __shfl(ed.x, i + 1);
      const u32 sC = __shfl(ed.x, i + 2), sD = __shfl(ed.x, i + 3);
      const u32 uA = xtw[(size_t)sA * 64 + lane];   // 4 gathers in flight
      const u32 uB = xtw[(size_t)sB * 64 + lane];
      const u32 uC = xtw[(size_t)sC * 64 + lane];
      const u32 uD = xtw[(size_t)sD * 64 + lane];
      const float wA = __uint_as_float(__shfl(ed.y, i));
      const float wB = __uint_as_float(__shfl(ed.y, i + 1));
      const float wC = __uint_as_float(__shfl(ed.y, i + 2));
      const float wD = __uint_as_float(__shfl(ed.y, i + 3));
      a0 += wA * bflo(uA) + wB * bflo(uB) + wC * bflo(uC) + wD * bflo(uD);
      a1 += wA * bfhi(uA) + wB * bfhi(uB) + wC * bfhi(uC) + wD * bfhi(uD);
    }
    for (; i < m; ++i) {
      const u32 s = __shfl(ed.x, i);
      const float w = __uint_as_float(__shfl(ed.y, i));
      const u32 u = xtw[(size_t)s * 64 + lane];
      a0 += w * bflo(u);
      a1 += w * bfhi(u);
    }
  }
  // finalize: expmap0 -> proj -> logmap0 -> relu -> expmap0 -> proj
  float n = fmaxf(sqrtf(wsum(a0 * a0 + a1 * a1)), MINNORM);
  float tn = fast_tanh(n);
  float m = tn * frcp(n);
  if (tn > MAXNORM) { m *= MAXNORM * frcp(tn); tn = MAXNORM; }
  float nn = fmaxf(tn, MINNORM);
  m *= fast_artanh(nn) * frcp(nn);
  float tA = fmaxf(m * a0, 0.f), tB = fmaxf(m * a1, 0.f);
  float nr = fmaxf(sqrtf(wsum(tA * tA + tB * tB)), MINNORM);
  float t2 = fast_tanh(nr);
  float m2 = t2 * frcp(nr);
  if (t2 > MAXNORM) m2 *= MAXNORM * frcp(t2);
  float oA = m2 * tA, oB = m2 * tB;
  if (bf) {
    u32 o = ((u32)f2bf(oA)) | (((u32)f2bf(oB)) << 16);
    ((u32*)out)[(size_t)node * 64 + lane] = o;
  } else {
    ((float2*)out)[(size_t)node * 64 + lane] = make_float2(oA, oB);
  }
}

extern "C" void kernel_launch(void* const* d_in, const int* in_sizes, int n_in,
                              void* d_out, int out_size, void* d_ws, size_t ws_size,
                              hipStream_t stream) {
  const void* x    = d_in[0];
  const void* W    = d_in[1];
  const void* bias = d_in[2];
  const int*  ei   = (const int*)d_in[3];
  const void* ew   = d_in[4];
  const int N = in_sizes[0] / D;
  const int E = in_sizes[4];

  char* ws = (char*)d_ws;
  size_t off = 0;
  auto carve = [&](size_t bytes) { char* p = ws + off; off = (off + bytes + 255) & ~(size_t)255; return p; };
  u16*   xt     = (u16*)  carve((size_t)N * D * sizeof(u16));    // 25.6 MB
  uint2* esrt   = (uint2*)carve((size_t)E * sizeof(uint2));      // 12.8 MB
  int*   offs   = (int*)  carve((size_t)(N + 1) * sizeof(int));
  int*   cursor = (int*)  carve((size_t)N * sizeof(int));
  int*   bins   = (int*)  carve((size_t)N * sizeof(int));
  int*   part   = (int*)  carve(1024 * sizeof(int));

  const int B = (N + 255) / 256;

  k0_zeroi<<<B, 256, 0, stream>>>(bins, N);
  OriginHyperbolicGraphConvolution_38628935860614_kernel<<<(N + 63) / 64, 256, 0, stream>>>(
      x, W, bias, xt, N);
  khist   <<<(E + 255) / 256, 256, 0, stream>>>(ei, bins, E, N);
  kscan1  <<<B, 256, 0, stream>>>(bins, offs, part, N);
  kscan2  <<<1, 1024, 0, stream>>>(part, offs, B, N);
  kscan3  <<<B, 256, 0, stream>>>(offs, cursor, part, N);
  kscatter<<<(E + 255) / 256, 256, 0, stream>>>(ei, ew, cursor, esrt, E, N);
  kagg    <<<(N + 3) / 4, 256, 0, stream>>>(offs, esrt, xt, d_out, x, N);
}